// Round 1
// baseline (161.755 us; speedup 1.0000x reference)
//
#include <hip/hip_runtime.h>
#include <math.h>

// ComplexBatchNorm2D: B=32, C=256, H=W=64, fp32.
// out[b,c,h,w,:] = A_c * (x[b,c,h,w,:] - mu_c) + beta_c
// with A_c = gamma_c @ W_c, W_c = (Cov_c + 2*EPS*I)^{-1/2} (EPS added twice in ref).

constexpr int   C_  = 256;
constexpr int   B_  = 32;
constexpr int   HW_ = 64 * 64;        // 4096 contiguous floats per (b,c) slab
constexpr float EPS_ = 1e-5f;

// ---------------- Pass 1: per-(b,c)-slab partial sums --------------------
__global__ __launch_bounds__(256) void k_partial(const float* __restrict__ xr,
                                                 const float* __restrict__ xi,
                                                 float* __restrict__ partial) {
    const int blk = blockIdx.x;               // blk = b*C + c  (slab index)
    const int tid = threadIdx.x;
    const float4* pr = (const float4*)xr + (size_t)blk * (HW_ / 4);
    const float4* pi = (const float4*)xi + (size_t)blk * (HW_ / 4);

    float sr = 0.f, si = 0.f, srr = 0.f, sii = 0.f, sri = 0.f;
#pragma unroll
    for (int it = 0; it < HW_ / 4 / 256; ++it) {     // 4 iterations
        float4 r = pr[tid + it * 256];
        float4 m = pi[tid + it * 256];
        sr  += (r.x + r.y) + (r.z + r.w);
        si  += (m.x + m.y) + (m.z + m.w);
        srr += (r.x * r.x + r.y * r.y) + (r.z * r.z + r.w * r.w);
        sii += (m.x * m.x + m.y * m.y) + (m.z * m.z + m.w * m.w);
        sri += (r.x * m.x + r.y * m.y) + (r.z * m.z + r.w * m.w);
    }

    // wave-64 butterfly-free down-reduce
#pragma unroll
    for (int off = 32; off > 0; off >>= 1) {
        sr  += __shfl_down(sr,  off);
        si  += __shfl_down(si,  off);
        srr += __shfl_down(srr, off);
        sii += __shfl_down(sii, off);
        sri += __shfl_down(sri, off);
    }

    __shared__ float red[4][5];
    const int wave = tid >> 6;
    if ((tid & 63) == 0) {
        red[wave][0] = sr;  red[wave][1] = si;  red[wave][2] = srr;
        red[wave][3] = sii; red[wave][4] = sri;
    }
    __syncthreads();
    if (tid < 5) {
        float v = (red[0][tid] + red[1][tid]) + (red[2][tid] + red[3][tid]);
        partial[(size_t)blk * 5 + tid] = v;
    }
}

// ---------------- Pass 2: fold partials -> per-channel affine ------------
__global__ __launch_bounds__(256) void k_params(const float* __restrict__ partial,
                                                const float* __restrict__ gamma,
                                                const float* __restrict__ beta,
                                                float* __restrict__ params) {
    const int c = threadIdx.x;                // one thread per channel
    float sr = 0.f, si = 0.f, srr = 0.f, sii = 0.f, sri = 0.f;
    for (int b = 0; b < B_; ++b) {
        const float* p = partial + ((size_t)b * C_ + c) * 5;
        sr += p[0]; si += p[1]; srr += p[2]; sii += p[3]; sri += p[4];
    }
    const float invN = 1.0f / (float)(B_ * HW_);
    const float mr = sr * invN, mi = si * invN;
    // cov gets +EPS*I, then M = cov + EPS*I  -> diagonal +2*EPS
    const float a  = srr * invN - mr * mr + 2.0f * EPS_;
    const float d  = sii * invN - mi * mi + 2.0f * EPS_;
    const float b2 = sri * invN - mr * mi;

    const float s   = sqrtf(a * d - b2 * b2);
    const float t   = sqrtf(a + d + 2.0f * s);
    const float inv = 1.0f / (s * t);
    const float W00 = (d + s) * inv;
    const float W11 = (a + s) * inv;
    const float W01 = -b2 * inv;              // symmetric: W10 == W01

    const float g00 = gamma[c * 4 + 0], g01 = gamma[c * 4 + 1];
    const float g10 = gamma[c * 4 + 2], g11 = gamma[c * 4 + 3];
    // A = gamma @ W
    const float A00 = g00 * W00 + g01 * W01;
    const float A01 = g00 * W01 + g01 * W11;
    const float A10 = g10 * W00 + g11 * W01;
    const float A11 = g10 * W01 + g11 * W11;
    const float b0 = beta[c * 2 + 0] - (A00 * mr + A01 * mi);
    const float b1 = beta[c * 2 + 1] - (A10 * mr + A11 * mi);

    float* o = params + c * 6;
    o[0] = A00; o[1] = A01; o[2] = A10; o[3] = A11; o[4] = b0; o[5] = b1;
}

// ---------------- Pass 3: normalize + interleave write -------------------
__global__ __launch_bounds__(256) void k_norm(const float* __restrict__ xr,
                                              const float* __restrict__ xi,
                                              const float* __restrict__ params,
                                              float* __restrict__ out) {
    const size_t nvec   = (size_t)B_ * C_ * HW_ / 4;     // 8M float4 pairs
    const size_t stride = (size_t)gridDim.x * blockDim.x;
    for (size_t v = (size_t)blockIdx.x * blockDim.x + threadIdx.x; v < nvec; v += stride) {
        const int c = (int)((v >> 10) & (C_ - 1));       // 1024 vecs per slab
        const float* p = params + c * 6;
        const float A00 = p[0], A01 = p[1], A10 = p[2], A11 = p[3], b0 = p[4], b1 = p[5];

        float4 r = ((const float4*)xr)[v];
        float4 m = ((const float4*)xi)[v];
        float4 o0, o1;
        o0.x = A00 * r.x + A01 * m.x + b0;
        o0.y = A10 * r.x + A11 * m.x + b1;
        o0.z = A00 * r.y + A01 * m.y + b0;
        o0.w = A10 * r.y + A11 * m.y + b1;
        o1.x = A00 * r.z + A01 * m.z + b0;
        o1.y = A10 * r.z + A11 * m.z + b1;
        o1.z = A00 * r.w + A01 * m.w + b0;
        o1.w = A10 * r.w + A11 * m.w + b1;

        float4* po = (float4*)out + v * 2;
        po[0] = o0;
        po[1] = o1;
    }
}

extern "C" void kernel_launch(void* const* d_in, const int* in_sizes, int n_in,
                              void* d_out, int out_size, void* d_ws, size_t ws_size,
                              hipStream_t stream) {
    const float* xr    = (const float*)d_in[0];
    const float* xi    = (const float*)d_in[1];
    const float* gamma = (const float*)d_in[2];
    const float* beta  = (const float*)d_in[3];
    float* out = (float*)d_out;

    float* partial = (float*)d_ws;                 // 8192*5 floats = 160 KB
    float* params  = partial + (size_t)B_ * C_ * 5; // 256*6 floats

    k_partial<<<B_ * C_, 256, 0, stream>>>(xr, xi, partial);
    k_params <<<1, 256, 0, stream>>>(partial, gamma, beta, params);
    k_norm   <<<2048, 256, 0, stream>>>(xr, xi, params, out);
}

// Round 2
// 148.410 us; speedup vs baseline: 1.0899x; 1.0899x over previous
//
#include <hip/hip_runtime.h>
#include <math.h>

// ComplexBatchNorm2D: B=32, C=256, H=W=64, fp32.
// out[b,c,h,w,:] = A_c * (x[b,c,h,w,:] - mu_c) + beta'_c
// A_c = gamma_c @ W_c, W_c = (Cov_c + 2*EPS*I)^{-1/2} (EPS added twice in ref),
// beta'_c = beta_c - A_c * mu_c.

constexpr int   C_  = 256;
constexpr int   B_  = 32;
constexpr int   HW_ = 64 * 64;        // 4096 contiguous floats per (b,c) slab
constexpr float EPS_ = 1e-5f;

typedef float f32x4 __attribute__((ext_vector_type(4)));

// ---------------- Pass 1: per-(b,c)-slab partial sums --------------------
__global__ __launch_bounds__(256) void k_partial(const float* __restrict__ xr,
                                                 const float* __restrict__ xi,
                                                 float* __restrict__ partial) {
    const int blk = blockIdx.x;               // blk = b*C + c  (slab index)
    const int tid = threadIdx.x;
    const float4* pr = (const float4*)xr + (size_t)blk * (HW_ / 4);
    const float4* pi = (const float4*)xi + (size_t)blk * (HW_ / 4);

    float sr = 0.f, si = 0.f, srr = 0.f, sii = 0.f, sri = 0.f;
#pragma unroll
    for (int it = 0; it < HW_ / 4 / 256; ++it) {     // 4 iterations
        float4 r = pr[tid + it * 256];
        float4 m = pi[tid + it * 256];
        sr  += (r.x + r.y) + (r.z + r.w);
        si  += (m.x + m.y) + (m.z + m.w);
        srr += (r.x * r.x + r.y * r.y) + (r.z * r.z + r.w * r.w);
        sii += (m.x * m.x + m.y * m.y) + (m.z * m.z + m.w * m.w);
        sri += (r.x * m.x + r.y * m.y) + (r.z * m.z + r.w * m.w);
    }

#pragma unroll
    for (int off = 32; off > 0; off >>= 1) {
        sr  += __shfl_down(sr,  off);
        si  += __shfl_down(si,  off);
        srr += __shfl_down(srr, off);
        sii += __shfl_down(sii, off);
        sri += __shfl_down(sri, off);
    }

    __shared__ float red[4][5];
    const int wave = tid >> 6;
    if ((tid & 63) == 0) {
        red[wave][0] = sr;  red[wave][1] = si;  red[wave][2] = srr;
        red[wave][3] = sii; red[wave][4] = sri;
    }
    __syncthreads();
    if (tid < 5) {
        float v = (red[0][tid] + red[1][tid]) + (red[2][tid] + red[3][tid]);
        partial[(size_t)blk * 5 + tid] = v;
    }
}

// ------- Pass 2 (fused): params for this block's 4 channels + normalize -------
// Block i owns slabs [4i, 4i+4); slab = b*C + c so 4 consecutive slabs are 4
// consecutive channels. 4 threads fold the 32 partials each (L2-hit reads),
// stash the affine in LDS, then all 256 threads stream 4096 float4 pairs.
__global__ __launch_bounds__(256) void k_norm(const float* __restrict__ xr,
                                              const float* __restrict__ xi,
                                              const float* __restrict__ partial,
                                              const float* __restrict__ gamma,
                                              const float* __restrict__ beta,
                                              float* __restrict__ out) {
    __shared__ float sp[4][6];                 // A00 A01 A10 A11 b0 b1
    const int tid = threadIdx.x;
    const int slab0 = blockIdx.x * 4;

    if (tid < 4) {
        const int c = (slab0 + tid) & (C_ - 1);
        float sr = 0.f, si = 0.f, srr = 0.f, sii = 0.f, sri = 0.f;
#pragma unroll 4
        for (int b = 0; b < B_; ++b) {
            const float* p = partial + ((size_t)b * C_ + c) * 5;
            sr += p[0]; si += p[1]; srr += p[2]; sii += p[3]; sri += p[4];
        }
        const float invN = 1.0f / (float)(B_ * HW_);
        const float mr = sr * invN, mi = si * invN;
        const float a  = srr * invN - mr * mr + 2.0f * EPS_;
        const float d  = sii * invN - mi * mi + 2.0f * EPS_;
        const float b2 = sri * invN - mr * mi;

        const float s   = sqrtf(a * d - b2 * b2);
        const float t   = sqrtf(a + d + 2.0f * s);
        const float inv = 1.0f / (s * t);
        const float W00 = (d + s) * inv;
        const float W11 = (a + s) * inv;
        const float W01 = -b2 * inv;           // symmetric

        const float g00 = gamma[c * 4 + 0], g01 = gamma[c * 4 + 1];
        const float g10 = gamma[c * 4 + 2], g11 = gamma[c * 4 + 3];
        const float A00 = g00 * W00 + g01 * W01;
        const float A01 = g00 * W01 + g01 * W11;
        const float A10 = g10 * W00 + g11 * W01;
        const float A11 = g10 * W01 + g11 * W11;
        sp[tid][0] = A00;
        sp[tid][1] = A01;
        sp[tid][2] = A10;
        sp[tid][3] = A11;
        sp[tid][4] = beta[c * 2 + 0] - (A00 * mr + A01 * mi);
        sp[tid][5] = beta[c * 2 + 1] - (A10 * mr + A11 * mi);
    }
    __syncthreads();

    const size_t vbase = (size_t)slab0 * (HW_ / 4);   // 4096 vecs per block
#pragma unroll
    for (int it = 0; it < 16; ++it) {
        const int vlocal = tid + it * 256;
        const int sl = vlocal >> 10;                  // local slab 0..3
        const float A00 = sp[sl][0], A01 = sp[sl][1];
        const float A10 = sp[sl][2], A11 = sp[sl][3];
        const float b0  = sp[sl][4], b1  = sp[sl][5];

        const size_t v = vbase + vlocal;
        float4 r = ((const float4*)xr)[v];
        float4 m = ((const float4*)xi)[v];
        f32x4 o0, o1;
        o0.x = A00 * r.x + A01 * m.x + b0;
        o0.y = A10 * r.x + A11 * m.x + b1;
        o0.z = A00 * r.y + A01 * m.y + b0;
        o0.w = A10 * r.y + A11 * m.y + b1;
        o1.x = A00 * r.z + A01 * m.z + b0;
        o1.y = A10 * r.z + A11 * m.z + b1;
        o1.z = A00 * r.w + A01 * m.w + b0;
        o1.w = A10 * r.w + A11 * m.w + b1;

        // Non-temporal: keep the (L3-resident) input from being evicted by
        // the 268 MB of output stores.
        f32x4* po = (f32x4*)out + v * 2;
        __builtin_nontemporal_store(o0, po);
        __builtin_nontemporal_store(o1, po + 1);
    }
}

extern "C" void kernel_launch(void* const* d_in, const int* in_sizes, int n_in,
                              void* d_out, int out_size, void* d_ws, size_t ws_size,
                              hipStream_t stream) {
    const float* xr    = (const float*)d_in[0];
    const float* xi    = (const float*)d_in[1];
    const float* gamma = (const float*)d_in[2];
    const float* beta  = (const float*)d_in[3];
    float* out = (float*)d_out;

    float* partial = (float*)d_ws;                 // 8192*5 floats = 160 KB

    k_partial<<<B_ * C_, 256, 0, stream>>>(xr, xi, partial);
    k_norm   <<<B_ * C_ / 4, 256, 0, stream>>>(xr, xi, partial, gamma, beta, out);
}